// Round 1
// baseline (771.145 us; speedup 1.0000x reference)
//
#include <hip/hip_runtime.h>
#include <math.h>

#define NV 100000
#define NK 64
#define NC 3
#define NF 16
#define EPS_W 1e-4f

// dims: 9 -> 64 -> 64 -> 64 -> 9, ELU on every layer (incl. last)

__device__ __forceinline__ float eluf(float x) {
    return x > 0.0f ? x : expm1f(x);
}

__launch_bounds__(256, 2)
__global__ void fused_pca_mlp(const float* __restrict__ coords,
                              const float* __restrict__ distsq,
                              const float* __restrict__ feats,
                              const int*   __restrict__ nidx,
                              const float* __restrict__ W0, const float* __restrict__ b0,
                              const float* __restrict__ W1, const float* __restrict__ b1,
                              const float* __restrict__ W2, const float* __restrict__ b2,
                              const float* __restrict__ W3, const float* __restrict__ b3,
                              float* __restrict__ out)
{
    // Transposed weights in LDS: sWt[j][i] so inner-i reads are contiguous float4.
    __shared__ __align__(16) float sW0t[64 * 9];    // [j][i]
    __shared__ __align__(16) float sW1t[64 * 64];
    __shared__ __align__(16) float sW2t[64 * 64];
    __shared__ __align__(16) float sW3t[9 * 64];
    __shared__ float sB0[64], sB1[64], sB2[64], sB3[9];

    const int tid = threadIdx.x;

    // ---- cooperative weight staging (transpose) ----
    for (int t = tid; t < 64 * 9; t += 256) {       // W0 [9,64] -> [64][9]
        int j = t / 9, i = t - j * 9;
        sW0t[t] = W0[i * 64 + j];
    }
    for (int t = tid; t < 64 * 64; t += 256) {      // W1 [64,64] -> [64][64]
        int j = t >> 6, i = t & 63;
        sW1t[t] = W1[i * 64 + j];
    }
    for (int t = tid; t < 64 * 64; t += 256) {
        int j = t >> 6, i = t & 63;
        sW2t[t] = W2[i * 64 + j];
    }
    for (int t = tid; t < 9 * 64; t += 256) {       // W3 [64,9] -> [9][64]
        int j = t >> 6, i = t & 63;
        sW3t[t] = W3[i * 9 + j];
    }
    if (tid < 64) { sB0[tid] = b0[tid]; sB1[tid] = b1[tid]; sB2[tid] = b2[tid]; }
    if (tid < 9)  { sB3[tid] = b3[tid]; }
    __syncthreads();

    // ---- thread = (vertex-in-block g, feature f); one MLP row per thread ----
    const int g = tid >> 4;          // 0..15
    const int f = tid & 15;          // 0..15
    const int v = blockIdx.x * 16 + g;
    if (v >= NV) return;             // V=100000 divides exactly; guard is free

    const int*   nix = nidx   + (size_t)v * NK;
    const float* dsq = distsq + (size_t)v * NK;

    // ---- neighbour covariance: 10 accumulators in registers ----
    float s = 0.f;
    float m0 = 0.f, m1 = 0.f, m2 = 0.f;
    float q00 = 0.f, q01 = 0.f, q02 = 0.f, q11 = 0.f, q12 = 0.f, q22 = 0.f;

    #pragma unroll 4
    for (int k = 0; k < NK; ++k) {
        int idx = nix[k];
        float ew = __expf(-10.0f * dsq[k]);
        float w  = feats[(size_t)idx * NF + f] * ew;   // coalesced across the 16 f-lanes
        float x  = coords[(size_t)idx * 3 + 0];
        float y  = coords[(size_t)idx * 3 + 1];
        float z  = coords[(size_t)idx * 3 + 2];
        s += w;
        m0 = fmaf(w, x, m0); m1 = fmaf(w, y, m1); m2 = fmaf(w, z, m2);
        float wx = w * x, wy = w * y, wz = w * z;
        q00 = fmaf(wx, x, q00); q01 = fmaf(wx, y, q01); q02 = fmaf(wx, z, q02);
        q11 = fmaf(wy, y, q11); q12 = fmaf(wy, z, q12);
        q22 = fmaf(wz, z, q22);
    }

    float inv = 1.0f / (s + EPS_W);
    float mu0 = m0 * inv, mu1 = m1 * inv, mu2 = m2 * inv;

    float xr[9];
    xr[0] = fmaf(-mu0, mu0, q00 * inv);
    xr[1] = fmaf(-mu0, mu1, q01 * inv);
    xr[2] = fmaf(-mu0, mu2, q02 * inv);
    xr[3] = xr[1];                                  // symmetric
    xr[4] = fmaf(-mu1, mu1, q11 * inv);
    xr[5] = fmaf(-mu1, mu2, q12 * inv);
    xr[6] = xr[2];
    xr[7] = xr[5];
    xr[8] = fmaf(-mu2, mu2, q22 * inv);

    // ---- MLP: fully unrolled so h/g stay in registers; LDS reads are
    // wave-uniform (broadcast, bank-conflict-free) ----
    float h[64], gg[64];

    // layer 0: 9 -> 64
    #pragma unroll
    for (int j = 0; j < 64; ++j) {
        float a = sB0[j];
        const float* wr = sW0t + j * 9;
        #pragma unroll
        for (int i = 0; i < 9; ++i) a = fmaf(xr[i], wr[i], a);
        h[j] = eluf(a);
    }
    // layer 1: 64 -> 64
    #pragma unroll
    for (int j = 0; j < 64; ++j) {
        float a = sB1[j];
        const float4* wr = (const float4*)(sW1t + (j << 6));
        #pragma unroll
        for (int i4 = 0; i4 < 16; ++i4) {
            float4 wv = wr[i4];
            a = fmaf(h[4 * i4 + 0], wv.x, a);
            a = fmaf(h[4 * i4 + 1], wv.y, a);
            a = fmaf(h[4 * i4 + 2], wv.z, a);
            a = fmaf(h[4 * i4 + 3], wv.w, a);
        }
        gg[j] = eluf(a);
    }
    // layer 2: 64 -> 64 (back into h)
    #pragma unroll
    for (int j = 0; j < 64; ++j) {
        float a = sB2[j];
        const float4* wr = (const float4*)(sW2t + (j << 6));
        #pragma unroll
        for (int i4 = 0; i4 < 16; ++i4) {
            float4 wv = wr[i4];
            a = fmaf(gg[4 * i4 + 0], wv.x, a);
            a = fmaf(gg[4 * i4 + 1], wv.y, a);
            a = fmaf(gg[4 * i4 + 2], wv.z, a);
            a = fmaf(gg[4 * i4 + 3], wv.w, a);
        }
        h[j] = eluf(a);
    }
    // layer 3: 64 -> 9
    float o[9];
    #pragma unroll
    for (int j = 0; j < 9; ++j) {
        float a = sB3[j];
        const float4* wr = (const float4*)(sW3t + (j << 6));
        #pragma unroll
        for (int i4 = 0; i4 < 16; ++i4) {
            float4 wv = wr[i4];
            a = fmaf(h[4 * i4 + 0], wv.x, a);
            a = fmaf(h[4 * i4 + 1], wv.y, a);
            a = fmaf(h[4 * i4 + 2], wv.z, a);
            a = fmaf(h[4 * i4 + 3], wv.w, a);
        }
        o[j] = eluf(a);
    }

    // ---- store: row (v*16+f), 9 floats ----
    float* op = out + ((size_t)v * NF + f) * 9;
    #pragma unroll
    for (int j = 0; j < 9; ++j) op[j] = o[j];
}

extern "C" void kernel_launch(void* const* d_in, const int* in_sizes, int n_in,
                              void* d_out, int out_size, void* d_ws, size_t ws_size,
                              hipStream_t stream) {
    const float* coords = (const float*)d_in[0];
    const float* distsq = (const float*)d_in[1];
    const float* feats  = (const float*)d_in[2];
    const int*   nidx   = (const int*)d_in[3];
    const float* W0 = (const float*)d_in[4];
    const float* b0 = (const float*)d_in[5];
    const float* W1 = (const float*)d_in[6];
    const float* b1 = (const float*)d_in[7];
    const float* W2 = (const float*)d_in[8];
    const float* b2 = (const float*)d_in[9];
    const float* W3 = (const float*)d_in[10];
    const float* b3 = (const float*)d_in[11];
    float* out = (float*)d_out;

    dim3 grid((NV + 15) / 16), block(256);
    hipLaunchKernelGGL(fused_pca_mlp, grid, block, 0, stream,
                       coords, distsq, feats, nidx,
                       W0, b0, W1, b1, W2, b2, W3, b3, out);
}

// Round 2
// 209.760 us; speedup vs baseline: 3.6763x; 3.6763x over previous
//
#include <hip/hip_runtime.h>
#include <math.h>

#define NV 100000
#define NK 64
#define NF 16
#define EPS_W 1e-4f
#define WS_NEED ((size_t)NV * 16 * 32)   // 51.2 MB: [V*F=1.6M rows][16 bf16]

typedef __attribute__((ext_vector_type(8))) short bf16x8;
typedef __attribute__((ext_vector_type(4))) float f32x4;

__device__ __forceinline__ unsigned int f2bfu(float x) {
    union { float f; unsigned int u; } a; a.f = x;
    return (a.u + 0x7FFFu + ((a.u >> 16) & 1u)) >> 16;   // RNE
}
__device__ __forceinline__ unsigned int packbf(float lo, float hi) {
    return f2bfu(lo) | (f2bfu(hi) << 16);
}
__device__ __forceinline__ float eluf(float x) {
    return x > 0.f ? x : __expf(x) - 1.f;
}

// ---------------------------------------------------------------------------
// Kernel A: neighbour covariance -> bf16 rows [v*16+f][16]:
//   dims 0-8 = cov(f,c,d), dim 9 = 1.0 (bias slot for layer-0 MFMA), 10-15 = 0
// ---------------------------------------------------------------------------
__launch_bounds__(256)
__global__ void cov_kernel(const float* __restrict__ coords,
                           const float* __restrict__ distsq,
                           const float* __restrict__ feats,
                           const int*   __restrict__ nidx,
                           unsigned char* __restrict__ ws)
{
    __shared__ float sEW[16][64];
    __shared__ int   sIX[16][64];
    const int tid = threadIdx.x;
    const int gv  = tid >> 4;          // vertex-in-block 0..15
    const int f   = tid & 15;          // feature 0..15
    const int v   = blockIdx.x * 16 + gv;

    // stage exp(-10*d2) and idx once per vertex (each thread does 4 k's)
    {
        const size_t base = (size_t)v * NK + 4 * f;
        float4 d4 = *(const float4*)(distsq + base);
        int4   i4 = *(const int4*)(nidx + base);
        sEW[gv][4*f+0] = __expf(-10.f * d4.x);
        sEW[gv][4*f+1] = __expf(-10.f * d4.y);
        sEW[gv][4*f+2] = __expf(-10.f * d4.z);
        sEW[gv][4*f+3] = __expf(-10.f * d4.w);
        sIX[gv][4*f+0] = i4.x; sIX[gv][4*f+1] = i4.y;
        sIX[gv][4*f+2] = i4.z; sIX[gv][4*f+3] = i4.w;
    }
    __syncthreads();

    float s = 0.f, m0=0.f,m1=0.f,m2=0.f;
    float q00=0.f,q01=0.f,q02=0.f,q11=0.f,q12=0.f,q22=0.f;

    #pragma unroll 4
    for (int k = 0; k < NK; ++k) {
        int   idx = sIX[gv][k];
        float ew  = sEW[gv][k];
        float w   = feats[(size_t)idx * NF + f] * ew;
        float x = coords[(size_t)idx*3+0];
        float y = coords[(size_t)idx*3+1];
        float z = coords[(size_t)idx*3+2];
        s += w;
        m0 = fmaf(w,x,m0); m1 = fmaf(w,y,m1); m2 = fmaf(w,z,m2);
        float wx=w*x, wy=w*y, wz=w*z;
        q00=fmaf(wx,x,q00); q01=fmaf(wx,y,q01); q02=fmaf(wx,z,q02);
        q11=fmaf(wy,y,q11); q12=fmaf(wy,z,q12); q22=fmaf(wz,z,q22);
    }
    float inv = 1.f / (s + EPS_W);
    float mu0=m0*inv, mu1=m1*inv, mu2=m2*inv;
    float c00=fmaf(-mu0,mu0,q00*inv);
    float c01=fmaf(-mu0,mu1,q01*inv);
    float c02=fmaf(-mu0,mu2,q02*inv);
    float c11=fmaf(-mu1,mu1,q11*inv);
    float c12=fmaf(-mu1,mu2,q12*inv);
    float c22=fmaf(-mu2,mu2,q22*inv);

    // row dims: [c00 c01 c02 | c01 c11 c12 | c02 c12 c22 | 1.0 | 0...]
    uint4 lo, hi;
    lo.x = packbf(c00, c01);
    lo.y = packbf(c02, c01);
    lo.z = packbf(c11, c12);
    lo.w = packbf(c02, c12);
    hi.x = packbf(c22, 1.0f);
    hi.y = 0u; hi.z = 0u; hi.w = 0u;

    uint4* dst = (uint4*)(ws + ((size_t)v * 16 + f) * 32);
    dst[0] = lo;
    dst[1] = hi;
}

// ---------------------------------------------------------------------------
// Kernel B: MFMA MLP. One wave = one vertex (16 rows).
// A-operand = W^T fragments in VGPRs; B-operand = activations, bounced
// through per-wave LDS with XOR swizzle (bits 4-6 ^= c&7).
// D layout (verified): col = lane&15, row = 4*(lane>>4)+reg.
// A/B layout: lane holds row/col = lane&15, k = 8*(lane>>4)+i.
// ---------------------------------------------------------------------------
__device__ __forceinline__ bf16x8 rdfrag(const short* hb, int c, int g, int kc) {
    int boff = ((kc << 6) + (g << 4)) ^ ((c & 7) << 4);
    return *(const bf16x8*)(hb + c * 64 + (boff >> 1));
}
__device__ __forceinline__ void wrH(short* hb, int c, int g, int t,
                                    unsigned int p01, unsigned int p23) {
    int boff = ((t << 5) + (g << 3)) ^ ((c & 7) << 4);
    uint2 val; val.x = p01; val.y = p23;
    *(uint2*)(hb + c * 64 + (boff >> 1)) = val;
}

__launch_bounds__(256, 2)
__global__ void mlp_kernel(const unsigned char* __restrict__ ws,
                           const float* __restrict__ W0, const float* __restrict__ b0,
                           const float* __restrict__ W1, const float* __restrict__ b1,
                           const float* __restrict__ W2, const float* __restrict__ b2,
                           const float* __restrict__ W3, const float* __restrict__ b3,
                           float* __restrict__ out)
{
    __shared__ __align__(16) short hbuf[4][16 * 64];
    const int tid  = threadIdx.x;
    const int wid  = tid >> 6;
    const int lane = tid & 63;
    const int c    = lane & 15;        // out-dim row (A) / batch col (B,D)
    const int g    = lane >> 4;        // k-group / D-row group
    short* hb = &hbuf[wid][0];

    union U8 { short s[8]; bf16x8 v; };

    // ---- weight fragments (one-time, per wave) ----
    bf16x8 w0f[4], w1f[8], w2f[8], w3f[2];
    #pragma unroll
    for (int t = 0; t < 4; ++t) {
        U8 u;
        #pragma unroll
        for (int i = 0; i < 8; ++i) {
            int k = 8 * g + i;
            float val = 0.f;
            if (k < 9)       val = W0[k * 64 + 16 * t + c];
            else if (k == 9) val = b0[16 * t + c];       // bias via dim-9=1.0
            u.s[i] = (short)f2bfu(val);
        }
        w0f[t] = u.v;
    }
    #pragma unroll
    for (int t = 0; t < 4; ++t) {
        #pragma unroll
        for (int kc = 0; kc < 2; ++kc) {
            U8 u1, u2;
            #pragma unroll
            for (int i = 0; i < 8; ++i) {
                int k = 32 * kc + 8 * g + i;
                u1.s[i] = (short)f2bfu(W1[k * 64 + 16 * t + c]);
                u2.s[i] = (short)f2bfu(W2[k * 64 + 16 * t + c]);
            }
            w1f[2 * t + kc] = u1.v;
            w2f[2 * t + kc] = u2.v;
        }
    }
    #pragma unroll
    for (int kc = 0; kc < 2; ++kc) {
        U8 u;
        #pragma unroll
        for (int i = 0; i < 8; ++i) {
            int k = 32 * kc + 8 * g + i;
            u.s[i] = (short)f2bfu(c < 9 ? W3[k * 9 + c] : 0.f);
        }
        w3f[kc] = u.v;
    }

    float b1v[16], b2v[16], b3v[4];
    #pragma unroll
    for (int t = 0; t < 4; ++t)
        #pragma unroll
        for (int r = 0; r < 4; ++r) {
            b1v[4*t+r] = b1[16*t + 4*g + r];
            b2v[4*t+r] = b2[16*t + 4*g + r];
        }
    #pragma unroll
    for (int r = 0; r < 4; ++r)
        b3v[r] = (4*g + r < 9) ? b3[4*g + r] : 0.f;

    // ---- tile loop: tile = vertex ----
    const int stride = gridDim.x * 4;
    for (int t0 = blockIdx.x * 4 + wid; t0 < NV; t0 += stride) {
        f32x4 a[4];
        // layer 0: B from global cov rows (K=32: g>=2 slots have zero A)
        {
            union { uint4 q; bf16x8 v; } bin;
            bin.q = *(const uint4*)(ws + (size_t)t0 * 512 + (c << 5) + ((g & 1) << 4));
            #pragma unroll
            for (int t = 0; t < 4; ++t) {
                f32x4 z4 = {0.f, 0.f, 0.f, 0.f};
                a[t] = __builtin_amdgcn_mfma_f32_16x16x32_bf16(w0f[t], bin.v, z4, 0, 0, 0);
            }
            #pragma unroll
            for (int t = 0; t < 4; ++t)
                wrH(hb, c, g, t, packbf(eluf(a[t][0]), eluf(a[t][1])),
                                 packbf(eluf(a[t][2]), eluf(a[t][3])));
        }
        // layer 1
        {
            bf16x8 h0 = rdfrag(hb, c, g, 0);
            bf16x8 h1 = rdfrag(hb, c, g, 1);
            #pragma unroll
            for (int t = 0; t < 4; ++t) {
                f32x4 acc = { b1v[4*t+0], b1v[4*t+1], b1v[4*t+2], b1v[4*t+3] };
                acc = __builtin_amdgcn_mfma_f32_16x16x32_bf16(w1f[2*t+0], h0, acc, 0, 0, 0);
                acc = __builtin_amdgcn_mfma_f32_16x16x32_bf16(w1f[2*t+1], h1, acc, 0, 0, 0);
                a[t] = acc;
            }
            #pragma unroll
            for (int t = 0; t < 4; ++t)
                wrH(hb, c, g, t, packbf(eluf(a[t][0]), eluf(a[t][1])),
                                 packbf(eluf(a[t][2]), eluf(a[t][3])));
        }
        // layer 2
        {
            bf16x8 h0 = rdfrag(hb, c, g, 0);
            bf16x8 h1 = rdfrag(hb, c, g, 1);
            #pragma unroll
            for (int t = 0; t < 4; ++t) {
                f32x4 acc = { b2v[4*t+0], b2v[4*t+1], b2v[4*t+2], b2v[4*t+3] };
                acc = __builtin_amdgcn_mfma_f32_16x16x32_bf16(w2f[2*t+0], h0, acc, 0, 0, 0);
                acc = __builtin_amdgcn_mfma_f32_16x16x32_bf16(w2f[2*t+1], h1, acc, 0, 0, 0);
                a[t] = acc;
            }
            #pragma unroll
            for (int t = 0; t < 4; ++t)
                wrH(hb, c, g, t, packbf(eluf(a[t][0]), eluf(a[t][1])),
                                 packbf(eluf(a[t][2]), eluf(a[t][3])));
        }
        // layer 3: 64 -> 9, single out-tile
        {
            bf16x8 h0 = rdfrag(hb, c, g, 0);
            bf16x8 h1 = rdfrag(hb, c, g, 1);
            f32x4 acc = { b3v[0], b3v[1], b3v[2], b3v[3] };
            acc = __builtin_amdgcn_mfma_f32_16x16x32_bf16(w3f[0], h0, acc, 0, 0, 0);
            acc = __builtin_amdgcn_mfma_f32_16x16x32_bf16(w3f[1], h1, acc, 0, 0, 0);
            float* op = out + (size_t)(t0 * 16 + c) * 9 + (g << 2);
            if (g < 2) {
                op[0] = eluf(acc[0]); op[1] = eluf(acc[1]);
                op[2] = eluf(acc[2]); op[3] = eluf(acc[3]);
            } else if (g == 2) {
                op[0] = eluf(acc[0]);   // dim 8
            }
        }
    }
}

// ---------------------------------------------------------------------------
// Fallback: round-1 fp32 fused kernel (used only if ws is too small)
// ---------------------------------------------------------------------------
__launch_bounds__(256, 2)
__global__ void fused_pca_mlp(const float* __restrict__ coords,
                              const float* __restrict__ distsq,
                              const float* __restrict__ feats,
                              const int*   __restrict__ nidx,
                              const float* __restrict__ W0, const float* __restrict__ b0,
                              const float* __restrict__ W1, const float* __restrict__ b1,
                              const float* __restrict__ W2, const float* __restrict__ b2,
                              const float* __restrict__ W3, const float* __restrict__ b3,
                              float* __restrict__ out)
{
    __shared__ __align__(16) float sW0t[64 * 9];
    __shared__ __align__(16) float sW1t[64 * 64];
    __shared__ __align__(16) float sW2t[64 * 64];
    __shared__ __align__(16) float sW3t[9 * 64];
    __shared__ float sB0[64], sB1[64], sB2[64], sB3[9];
    const int tid = threadIdx.x;
    for (int t = tid; t < 64 * 9; t += 256) { int j = t / 9, i = t - j * 9; sW0t[t] = W0[i * 64 + j]; }
    for (int t = tid; t < 64 * 64; t += 256) { int j = t >> 6, i = t & 63; sW1t[t] = W1[i * 64 + j]; }
    for (int t = tid; t < 64 * 64; t += 256) { int j = t >> 6, i = t & 63; sW2t[t] = W2[i * 64 + j]; }
    for (int t = tid; t < 9 * 64; t += 256) { int j = t >> 6, i = t & 63; sW3t[t] = W3[i * 9 + j]; }
    if (tid < 64) { sB0[tid] = b0[tid]; sB1[tid] = b1[tid]; sB2[tid] = b2[tid]; }
    if (tid < 9)  { sB3[tid] = b3[tid]; }
    __syncthreads();
    const int g = tid >> 4, f = tid & 15;
    const int v = blockIdx.x * 16 + g;
    if (v >= NV) return;
    const int* nix = nidx + (size_t)v * NK;
    const float* dsq = distsq + (size_t)v * NK;
    float s = 0.f, m0=0,m1=0,m2=0, q00=0,q01=0,q02=0,q11=0,q12=0,q22=0;
    #pragma unroll 4
    for (int k = 0; k < NK; ++k) {
        int idx = nix[k];
        float ew = __expf(-10.0f * dsq[k]);
        float w = feats[(size_t)idx * NF + f] * ew;
        float x = coords[(size_t)idx*3+0], y = coords[(size_t)idx*3+1], z = coords[(size_t)idx*3+2];
        s += w; m0 = fmaf(w,x,m0); m1 = fmaf(w,y,m1); m2 = fmaf(w,z,m2);
        float wx=w*x, wy=w*y, wz=w*z;
        q00=fmaf(wx,x,q00); q01=fmaf(wx,y,q01); q02=fmaf(wx,z,q02);
        q11=fmaf(wy,y,q11); q12=fmaf(wy,z,q12); q22=fmaf(wz,z,q22);
    }
    float inv = 1.0f/(s+EPS_W), mu0=m0*inv, mu1=m1*inv, mu2=m2*inv;
    float xr[9];
    xr[0]=fmaf(-mu0,mu0,q00*inv); xr[1]=fmaf(-mu0,mu1,q01*inv); xr[2]=fmaf(-mu0,mu2,q02*inv);
    xr[3]=xr[1]; xr[4]=fmaf(-mu1,mu1,q11*inv); xr[5]=fmaf(-mu1,mu2,q12*inv);
    xr[6]=xr[2]; xr[7]=xr[5]; xr[8]=fmaf(-mu2,mu2,q22*inv);
    float h[64], gg[64];
    #pragma unroll
    for (int j = 0; j < 64; ++j) {
        float aa = sB0[j]; const float* wr = sW0t + j * 9;
        #pragma unroll
        for (int i = 0; i < 9; ++i) aa = fmaf(xr[i], wr[i], aa);
        h[j] = eluf(aa);
    }
    #pragma unroll
    for (int j = 0; j < 64; ++j) {
        float aa = sB1[j]; const float4* wr = (const float4*)(sW1t + (j << 6));
        #pragma unroll
        for (int i4 = 0; i4 < 16; ++i4) { float4 wv = wr[i4];
            aa = fmaf(h[4*i4+0],wv.x,aa); aa = fmaf(h[4*i4+1],wv.y,aa);
            aa = fmaf(h[4*i4+2],wv.z,aa); aa = fmaf(h[4*i4+3],wv.w,aa); }
        gg[j] = eluf(aa);
    }
    #pragma unroll
    for (int j = 0; j < 64; ++j) {
        float aa = sB2[j]; const float4* wr = (const float4*)(sW2t + (j << 6));
        #pragma unroll
        for (int i4 = 0; i4 < 16; ++i4) { float4 wv = wr[i4];
            aa = fmaf(gg[4*i4+0],wv.x,aa); aa = fmaf(gg[4*i4+1],wv.y,aa);
            aa = fmaf(gg[4*i4+2],wv.z,aa); aa = fmaf(gg[4*i4+3],wv.w,aa); }
        h[j] = eluf(aa);
    }
    float o[9];
    #pragma unroll
    for (int j = 0; j < 9; ++j) {
        float aa = sB3[j]; const float4* wr = (const float4*)(sW3t + (j << 6));
        #pragma unroll
        for (int i4 = 0; i4 < 16; ++i4) { float4 wv = wr[i4];
            aa = fmaf(h[4*i4+0],wv.x,aa); aa = fmaf(h[4*i4+1],wv.y,aa);
            aa = fmaf(h[4*i4+2],wv.z,aa); aa = fmaf(h[4*i4+3],wv.w,aa); }
        o[j] = eluf(aa);
    }
    float* op = out + ((size_t)v * NF + f) * 9;
    #pragma unroll
    for (int j = 0; j < 9; ++j) op[j] = o[j];
}

extern "C" void kernel_launch(void* const* d_in, const int* in_sizes, int n_in,
                              void* d_out, int out_size, void* d_ws, size_t ws_size,
                              hipStream_t stream) {
    (void)in_sizes; (void)n_in; (void)out_size;
    const float* coords = (const float*)d_in[0];
    const float* distsq = (const float*)d_in[1];
    const float* feats  = (const float*)d_in[2];
    const int*   nidx   = (const int*)d_in[3];
    const float* W0 = (const float*)d_in[4];
    const float* b0 = (const float*)d_in[5];
    const float* W1 = (const float*)d_in[6];
    const float* b1 = (const float*)d_in[7];
    const float* W2 = (const float*)d_in[8];
    const float* b2 = (const float*)d_in[9];
    const float* W3 = (const float*)d_in[10];
    const float* b3 = (const float*)d_in[11];
    float* out = (float*)d_out;

    if (ws_size >= WS_NEED) {
        unsigned char* ws = (unsigned char*)d_ws;
        hipLaunchKernelGGL(cov_kernel, dim3(NV / 16), dim3(256), 0, stream,
                           coords, distsq, feats, nidx, ws);
        hipLaunchKernelGGL(mlp_kernel, dim3(1024), dim3(256), 0, stream,
                           ws, W0, b0, W1, b1, W2, b2, W3, b3, out);
    } else {
        hipLaunchKernelGGL(fused_pca_mlp, dim3(NV / 16), dim3(256), 0, stream,
                           coords, distsq, feats, nidx,
                           W0, b0, W1, b1, W2, b2, W3, b3, out);
    }
}